// Round 4
// baseline (857.659 us; speedup 1.0000x reference)
//
#include <hip/hip_runtime.h>
#include <hip/hip_bf16.h>

typedef __hip_bfloat16 bf16;
typedef __bf16 bf16x8 __attribute__((ext_vector_type(8)));
typedef float f32x4 __attribute__((ext_vector_type(4)));

#define NU 40000
#define NI 60000
#define NN 100000
#define DF 1024
#define DL 128
#define DI 64
#define NE 1600000
#define CAP 64

__device__ __forceinline__ float leaky(float v) { return v > 0.0f ? v : 0.01f * v; }

// f32 -> bf16 round-to-nearest-even
__device__ __forceinline__ unsigned short f2b(float f) {
    unsigned u = __builtin_bit_cast(unsigned, f);
    unsigned r = (u + 0x7FFFu + ((u >> 16) & 1u)) >> 16;
    return (unsigned short)r;
}
__device__ __forceinline__ bf16 tobf(float f) {
    unsigned short r = f2b(f);
    return __builtin_bit_cast(bf16, r);
}
__device__ __forceinline__ unsigned pk2(float x, float y) {
    return (unsigned)f2b(x) | ((unsigned)f2b(y) << 16);
}
// stage 8 consecutive elements into LDS (T=bf16: raw copy; T=float: convert)
template<typename T>
__device__ __forceinline__ void stage8(bf16* dst, const T* src) {
    if constexpr (sizeof(T) == 2) {
        *(uint4*)dst = *(const uint4*)src;
    } else {
        float4 a = *(const float4*)src;
        float4 b = *(const float4*)(src + 4);
        uint2 lo, hi;
        lo.x = pk2(a.x, a.y); lo.y = pk2(a.z, a.w);
        hi.x = pk2(b.x, b.y); hi.y = pk2(b.z, b.w);
        *(uint2*)dst = lo;
        *(uint2*)(dst + 4) = hi;
    }
}
__device__ __forceinline__ void zero8(bf16* dst) {
    uint4 z = {0u, 0u, 0u, 0u};
    *(uint4*)dst = z;
}

// ---------------- CSR (bucket) build ----------------
__global__ void csr_fill(const int* __restrict__ ei, int* __restrict__ cnt,
                         int* __restrict__ bucket) {
    int e = blockIdx.x * 256 + threadIdx.x;
    if (e >= NE) return;
    int s = ei[e];          // src
    int d = ei[NE + e];     // dst
    int p = atomicAdd(&cnt[d], 1);
    if (p < CAP) bucket[d * CAP + p] = s;
}

// ---------------- weight transpose+convert ([K,M] f32 -> [M,K] bf16) ----------------
template<int K, int M>
__global__ void transpose_kernel(const float* __restrict__ W, bf16* __restrict__ Wt) {
    int idx = blockIdx.x * 256 + threadIdx.x;
    if (idx < K * M) {
        int k = idx / M, m = idx % M;
        Wt[m * K + k] = tobf(W[k * M + m]);
    }
}

// ---------------- GEMM1: temp[NI,DL] = features[NI,DF] @ mlp_w[DL,DF]^T + mlp_b ----
__global__ __launch_bounds__(256) void gemm1_kernel(const float* __restrict__ A,
                                                    const float* __restrict__ W,
                                                    const float* __restrict__ bias,
                                                    bf16* __restrict__ out) {
    __shared__ __align__(16) bf16 As[128 * 64];
    __shared__ __align__(16) bf16 Bs[128 * 64];
    int t = threadIdx.x;
    int wave = t >> 6, lane = t & 63;
    int q = lane >> 4, l16 = lane & 15;
    int row0 = blockIdx.x * 128;
    f32x4 acc[2][8] = {};
    for (int k0 = 0; k0 < DF; k0 += 64) {
        #pragma unroll
        for (int i = 0; i < 4; i++) {
            int slot = t + i * 256;           // 1024 slots of 8 elements
            int r = slot >> 3;
            int kc = (slot & 7) * 8;
            int gr = row0 + r;
            if (gr < NI) stage8(As + r * 64 + kc, A + (size_t)gr * DF + k0 + kc);
            else         zero8(As + r * 64 + kc);
            stage8(Bs + r * 64 + kc, W + (size_t)r * DF + k0 + kc);
        }
        __syncthreads();
        #pragma unroll
        for (int kk = 0; kk < 64; kk += 32) {
            bf16x8 a0 = *(const bf16x8*)(As + (wave * 32 + l16) * 64 + kk + q * 8);
            bf16x8 a1 = *(const bf16x8*)(As + (wave * 32 + 16 + l16) * 64 + kk + q * 8);
            #pragma unroll
            for (int nt = 0; nt < 8; nt++) {
                bf16x8 b = *(const bf16x8*)(Bs + (nt * 16 + l16) * 64 + kk + q * 8);
                acc[0][nt] = __builtin_amdgcn_mfma_f32_16x16x32_bf16(a0, b, acc[0][nt], 0, 0, 0);
                acc[1][nt] = __builtin_amdgcn_mfma_f32_16x16x32_bf16(a1, b, acc[1][nt], 0, 0, 0);
            }
        }
        __syncthreads();
    }
    #pragma unroll
    for (int mt = 0; mt < 2; mt++) {
        #pragma unroll
        for (int nt = 0; nt < 8; nt++) {
            int col = nt * 16 + l16;
            float bv = bias[col];
            #pragma unroll
            for (int r = 0; r < 4; r++) {
                int row = row0 + wave * 32 + mt * 16 + q * 4 + r;
                if (row < NI) out[(size_t)row * DL + col] = tobf(acc[mt][nt][r] + bv);
            }
        }
    }
}

// ---------------- normalize + concat -> x0[NN,DL] ----------------
__global__ __launch_bounds__(256) void norm_kernel(const float* __restrict__ pref,
                                                   const bf16* __restrict__ temp,
                                                   bf16* __restrict__ x0) {
    __shared__ float wsum[4];
    int t = threadIdx.x;
    int g = t >> 7;            // 2 rows per 256-thread block
    int c = t & 127;
    int row = blockIdx.x * 2 + g;
    float v = (row < NU) ? pref[(size_t)row * DL + c]
                         : (float)temp[(size_t)(row - NU) * DL + c];
    float ss = v * v;
    #pragma unroll
    for (int off = 32; off > 0; off >>= 1) ss += __shfl_down(ss, off);
    int wave = t >> 6;
    if ((t & 63) == 0) wsum[wave] = ss;
    __syncthreads();
    float tot = wsum[g * 2] + wsum[g * 2 + 1];
    float inv = 1.0f / fmaxf(sqrtf(tot), 1e-12f);
    x0[(size_t)row * DL + c] = tobf(v * inv);
}

// ---------------- generic small GEMM with fused epilogue ----------------
// C[nrows,M] = A[nrows,K](bf16) @ Wt[M,K](WT)^T
// EPI 0: out = z                               (OutT=bf16)
// EPI 1: out = leaky(z + bias) + extra         (extra f32 id_emb, OutT=float)
// EPI 2: out = leaky(z + bias + extra)         (extra f32 xhat,   OutT=bf16|float)
template<typename WT, int K, int M, int EPI, typename OutT>
__global__ __launch_bounds__(256) void sgemm_kernel(const bf16* __restrict__ A,
                                                    const WT* __restrict__ Wt,
                                                    const float* __restrict__ bias,
                                                    const float* __restrict__ extra,
                                                    OutT* __restrict__ out,
                                                    int nrows) {
    __shared__ __align__(16) bf16 As[128 * K];
    __shared__ __align__(16) bf16 Ws[M * K];
    int t = threadIdx.x;
    int wave = t >> 6, lane = t & 63;
    int q = lane >> 4, l16 = lane & 15;
    int row0 = blockIdx.x * 128;
    constexpr int WSLOT = M * K / 8;
    for (int slot = t; slot < WSLOT; slot += 256)
        stage8(Ws + slot * 8, Wt + (size_t)slot * 8);
    constexpr int SLOTS = 128 * K / 8;
    for (int slot = t; slot < SLOTS; slot += 256) {
        int r = slot / (K / 8);
        int kc = (slot % (K / 8)) * 8;
        int gr = row0 + r;
        if (gr < nrows) *(uint4*)(As + r * K + kc) = *(const uint4*)(A + (size_t)gr * K + kc);
        else            zero8(As + r * K + kc);
    }
    __syncthreads();
    constexpr int NT = M / 16;
    f32x4 acc[2][NT] = {};
    #pragma unroll
    for (int kk = 0; kk < K; kk += 32) {
        bf16x8 a0 = *(const bf16x8*)(As + (wave * 32 + l16) * K + kk + q * 8);
        bf16x8 a1 = *(const bf16x8*)(As + (wave * 32 + 16 + l16) * K + kk + q * 8);
        #pragma unroll
        for (int nt = 0; nt < NT; nt++) {
            bf16x8 b = *(const bf16x8*)(Ws + (nt * 16 + l16) * K + kk + q * 8);
            acc[0][nt] = __builtin_amdgcn_mfma_f32_16x16x32_bf16(a0, b, acc[0][nt], 0, 0, 0);
            acc[1][nt] = __builtin_amdgcn_mfma_f32_16x16x32_bf16(a1, b, acc[1][nt], 0, 0, 0);
        }
    }
    #pragma unroll
    for (int mt = 0; mt < 2; mt++) {
        #pragma unroll
        for (int nt = 0; nt < NT; nt++) {
            int col = nt * 16 + l16;
            float bv = (EPI != 0) ? bias[col] : 0.0f;
            #pragma unroll
            for (int r = 0; r < 4; r++) {
                int row = row0 + wave * 32 + mt * 16 + q * 4 + r;
                if (row < nrows) {
                    float z = acc[mt][nt][r];
                    if (EPI == 1) {
                        z = leaky(z + bv) + extra[(size_t)row * M + col];
                    } else if (EPI == 2) {
                        z = leaky(z + bv + extra[(size_t)row * M + col]);
                    }
                    if constexpr (sizeof(OutT) == 2) out[(size_t)row * M + col] = tobf(z);
                    else                             out[(size_t)row * M + col] = z;
                }
            }
        }
    }
}

// ---------------- gather + leaky: h[d,:] = leaky(sum over in-edges of xw[src,:]) ----
template<int D>
__global__ __launch_bounds__(256) void gather_kernel(const bf16* __restrict__ xw,
                                                     const int* __restrict__ cnt,
                                                     const int* __restrict__ bucket,
                                                     bf16* __restrict__ h) {
    constexpr int GP = 256 / D;
    __shared__ int srcs[GP][CAP];
    int g = threadIdx.x / D;
    int c = threadIdx.x % D;
    int node = blockIdx.x * GP + g;
    int deg = min(cnt[node], CAP);
    for (int i = c; i < deg; i += D) srcs[g][i] = bucket[node * CAP + i];
    __syncthreads();
    float sum = 0.0f;
    for (int i = 0; i < deg; i++) {
        int s = srcs[g][i];
        sum += (float)xw[(size_t)s * D + c];
    }
    h[(size_t)node * D + c] = tobf(leaky(sum));
}

extern "C" void kernel_launch(void* const* d_in, const int* in_sizes, int n_in,
                              void* d_out, int out_size, void* d_ws, size_t ws_size,
                              hipStream_t stream) {
    // Robust input mapping by element count (canonical setup_inputs order as fallback).
    const void* p[16];
    for (int i = 0; i < 16 && i < n_in; i++) p[i] = d_in[i];
    if (n_in == 16) {
        int n8192 = 0, n4096 = 0, n64 = 0;
        const int idx64[4] = {7, 9, 12, 14};
        const int idx4096[3] = {10, 11, 13};
        for (int i = 0; i < 16; i++) {
            switch (in_sizes[i]) {
                case 61440000: p[0] = d_in[i]; break;                  // features
                case 6400000:  p[1] = d_in[i]; break;                  // id_embedding
                case 5120000:  p[2] = d_in[i]; break;                  // preference
                case 131072:   p[3] = d_in[i]; break;                  // mlp_w
                case 128:      p[4] = d_in[i]; break;                  // mlp_b
                case 16384:    p[5] = d_in[i]; break;                  // conv1_w
                case 8192:     p[n8192++ ? 8 : 6] = d_in[i]; break;    // lin1_w, g1_w
                case 64:       if (n64 < 4) p[idx64[n64++]] = d_in[i]; break;
                case 4096:     if (n4096 < 3) p[idx4096[n4096++]] = d_in[i]; break;
                case 3200000:  p[15] = d_in[i]; break;                 // edge_index
                default: break;
            }
        }
    }
    const float* features = (const float*)p[0];
    const float* id_emb   = (const float*)p[1];
    const float* pref     = (const float*)p[2];
    const float* mlp_w    = (const float*)p[3];
    const float* mlp_b    = (const float*)p[4];
    const float* conv1_w  = (const float*)p[5];
    const float* lin1_w   = (const float*)p[6];
    const float* lin1_b   = (const float*)p[7];
    const float* g1_w     = (const float*)p[8];
    const float* g1_b     = (const float*)p[9];
    const float* conv2_w  = (const float*)p[10];
    const float* lin2_w   = (const float*)p[11];
    const float* lin2_b   = (const float*)p[12];
    const float* g2_w     = (const float*)p[13];
    const float* g2_b     = (const float*)p[14];
    const int*   ei       = (const int*)p[15];

    char* wsp = (char*)d_ws;
    size_t off = 0;
    auto alloc = [&](size_t bytes) {
        void* ptr = wsp + off;
        off += (bytes + 255) & ~(size_t)255;
        return ptr;
    };
    // regions (sequential lifetimes), ~103 MB total:
    //   A: temp[NI,128]bf16 -> h1[NN,128]bf16 -> h2[NN,64]bf16
    //   B: x0[NN,128]bf16   -> xw2[NN,64]bf16
    //   C: xw1[NN,128]bf16  -> xhat[NN,64]f32 (layer1 then layer2)
    //   x1[NN,64]bf16 lives in d_out's first half (dead before final f32 write)
    void* regA = alloc((size_t)NN * DL * 2);
    void* regB = alloc((size_t)NN * DL * 2);
    void* regC = alloc((size_t)NN * DL * 2);
    int*  cnt    = (int*) alloc((size_t)NN * 4);
    int*  bucket = (int*) alloc((size_t)NN * CAP * 4);
    bf16* c1t    = (bf16*)alloc((size_t)DL * DL * 2);
    bf16* c2t    = (bf16*)alloc((size_t)DI * DI * 2);

    bf16*  temp = (bf16*)regA;
    bf16*  h1   = (bf16*)regA;
    bf16*  h2   = (bf16*)regA;
    bf16*  x0   = (bf16*)regB;
    bf16*  xw2  = (bf16*)regB;
    bf16*  xw1  = (bf16*)regC;
    float* xhat = (float*)regC;
    bf16*  x1   = (bf16*)d_out;       // scratch in output buffer (f32-sized)
    float* out  = (float*)d_out;      // final output: float32

    hipMemsetAsync(cnt, 0, (size_t)NN * 4, stream);
    csr_fill<<<NE / 256, 256, 0, stream>>>(ei, cnt, bucket);

    transpose_kernel<DL, DL><<<(DL * DL + 255) / 256, 256, 0, stream>>>(conv1_w, c1t);
    transpose_kernel<DI, DI><<<(DI * DI + 255) / 256, 256, 0, stream>>>(conv2_w, c2t);

    gemm1_kernel<<<(NI + 127) / 128, 256, 0, stream>>>(features, mlp_w, mlp_b, temp);
    norm_kernel<<<NN / 2, 256, 0, stream>>>(pref, temp, x0);

    const int SG = (NN + 127) / 128;
    // ----- layer 1 -----
    sgemm_kernel<bf16, DL, DL, 0, bf16><<<SG, 256, 0, stream>>>(x0, c1t, nullptr, nullptr, xw1, NN);
    gather_kernel<DL><<<NN / 2, 256, 0, stream>>>(xw1, cnt, bucket, h1);
    sgemm_kernel<float, DL, DI, 1, float><<<SG, 256, 0, stream>>>(x0, lin1_w, lin1_b, id_emb, xhat, NN);
    sgemm_kernel<float, DL, DI, 2, bf16><<<SG, 256, 0, stream>>>(h1, g1_w, g1_b, xhat, x1, NN);
    // ----- layer 2 -----
    sgemm_kernel<float, DI, DI, 1, float><<<SG, 256, 0, stream>>>(x1, lin2_w, lin2_b, id_emb, xhat, NN);
    sgemm_kernel<bf16, DI, DI, 0, bf16><<<SG, 256, 0, stream>>>(x1, c2t, nullptr, nullptr, xw2, NN);
    gather_kernel<DI><<<NN / 4, 256, 0, stream>>>(xw2, cnt, bucket, h2);
    sgemm_kernel<float, DI, DI, 2, float><<<SG, 256, 0, stream>>>(h2, g2_w, g2_b, xhat, out, NN);
}